// Round 6
// baseline (107.025 us; speedup 1.0000x reference)
//
#include <hip/hip_runtime.h>

// Problem constants (fixed by the reference)
#define B_TOT 16384
#define TBB   16        // batch rows per block
#define NTH   512       // 8 waves; wave wv handles n in [4wv, 4wv+4)
#define SLS   524       // f32 stride of sL row (verified R2/R4/R5)

typedef short bf16x8 __attribute__((ext_vector_type(8)));
typedef float f32x4  __attribute__((ext_vector_type(4)));
union U4 { bf16x8 v; uint4 q; };

__device__ __forceinline__ unsigned f2bf(float f) {
    unsigned u = __float_as_uint(f);
    return (u + 0x7fffu + ((u >> 16) & 1u)) >> 16;   // RNE
}

__device__ __forceinline__ uint4 packrow(const float* src) {   // 8 W elems, i-stride 16
    uint4 o;
    o.x = f2bf(src[0])  | (f2bf(src[16])  << 16);
    o.y = f2bf(src[32]) | (f2bf(src[48])  << 16);
    o.z = f2bf(src[64]) | (f2bf(src[80])  << 16);
    o.w = f2bf(src[96]) | (f2bf(src[112]) << 16);
    return o;
}

// Wk[n][s][lane] (uint4): K=32 packed A-frag; lane (q=l>>4, z=l&15) holds
// W[n][4s+q][i=0..7][z]. Per-j fragments derived in registers by AND-masking
// lane-quarter q == (j&3) (bit-identical to prepacked zero-octet frags — R4/R5).
__global__ void prepack(const float* __restrict__ W, uint4* __restrict__ Wp)
{
    const int t = blockIdx.x * 256 + threadIdx.x;   // 8192 threads
    const int lane = t & 63, s = (t >> 6) & 3, n = t >> 8;
    const int q = lane >> 4, z = lane & 15;
    Wp[t] = packrow(W + (size_t)(n * 16 + 4 * s + q) * 128 + z);
}

// D-mapping (m89-verified, identical to PASSING R4/R5): col = lane&15 = b, row = 4q+reg = z.
__global__ __launch_bounds__(NTH, 8)
void caps(const float* __restrict__ X, const uint4* __restrict__ Wp,
          const float* __restrict__ Bias, float* __restrict__ Out)
{
    __shared__ __align__(16) float sL[TBB * SLS];   // logits -> c+bias, f32 (33.5 KB)
    __shared__ float sBias[512];

    const int t    = threadIdx.x;
    const int lane = t & 63;
    const int wv   = t >> 6;          // 0..7
    const int b16  = lane & 15;       // D col = batch row
    const int q    = lane >> 4;       // lane quarter = K-octet = z-row group
    const long bb  = (long)blockIdx.x * TBB;

    sBias[t] = Bias[t];

    // per-octet lane masks: moct[c] = ~0 iff this lane's quarter q == c
    unsigned moct[4];
    #pragma unroll
    for (int c = 0; c < 4; ++c) moct[c] = (q == c) ? 0xffffffffu : 0u;

    // x B-frags, K=32 packed (4 j per frag): frag s, lane (q,b16) = x[b16][4s+q][0..7]
    uint4 xq[4];
    #pragma unroll
    for (int s = 0; s < 4; ++s) {
        const float* xs = X + (bb + b16) * 128 + (4 * s + q) * 8;
        float4 a = *reinterpret_cast<const float4*>(xs);
        float4 c = *reinterpret_cast<const float4*>(xs + 4);
        uint4 o;
        o.x = f2bf(a.x) | (f2bf(a.y) << 16);
        o.y = f2bf(a.z) | (f2bf(a.w) << 16);
        o.z = f2bf(c.x) | (f2bf(c.y) << 16);
        o.w = f2bf(c.z) | (f2bf(c.w) << 16);
        xq[s] = o;
    }

    const f32x4 zero4 = {0.f, 0.f, 0.f, 0.f};

    // masked per-j A-frag from the K=32 frag (4 v_and; bit-identical to R4 wj loads)
    auto maskA = [&](const uint4& wkf, int c) {
        U4 a;
        const unsigned m = moct[c];
        a.q.x = wkf.x & m; a.q.y = wkf.y & m;
        a.q.z = wkf.z & m; a.q.w = wkf.w & m;
        return a;
    };

    uint4 wk[4];

    // ---------------- pass 1: logits for this wave's 4 n ----------------
    #pragma unroll 1
    for (int nq = 0; nq < 4; ++nq) {
        const int n = wv * 4 + nq;
        const uint4* pw = Wp + n * 256 + lane;
        wk[0] = pw[0]; wk[1] = pw[64]; wk[2] = pw[128]; wk[3] = pw[192];

        f32x4 usum = zero4;                         // usum[b,z]: 4 chained MFMAs
        #pragma unroll
        for (int s = 0; s < 4; ++s) {
            U4 a;  a.q  = wk[s];
            U4 xb; xb.q = xq[s];
            usum = __builtin_amdgcn_mfma_f32_16x16x32_bf16(a.v, xb.v, usum, 0, 0, 0);
        }

        float lv[4];
        #pragma unroll
        for (int j = 0; j < 16; ++j) {              // 16 per-j MFMAs, zero loads
            U4 a  = maskA(wk[j >> 2], j & 3);
            U4 xb; xb.q = xq[j >> 2];
            f32x4 u = __builtin_amdgcn_mfma_f32_16x16x32_bf16(a.v, xb.v, zero4, 0, 0, 0);
            float p = u[0] * usum[0];
            p = fmaf(u[1], usum[1], p);
            p = fmaf(u[2], usum[2], p);
            p = fmaf(u[3], usum[3], p);
            p += __shfl_xor(p, 16);                 // sum the 4 z-quarters
            p += __shfl_xor(p, 32);
            lv[j & 3] = p * 0.25f;                  // /sqrt(D)
            if ((j & 3) == 3 && lane < 16)          // flush each 4-j chunk
                *reinterpret_cast<float4*>(&sL[b16 * SLS + n * 16 + (j - 3)]) =
                    make_float4(lv[0], lv[1], lv[2], lv[3]);
        }
    }
    __syncthreads();

    // ---------------- softmax over n (+ bias), one (b,j) per thread ----------------
    if (t < 256) {
        const int sb = t >> 4, sj = t & 15;
        float l[32];
        #pragma unroll
        for (int n = 0; n < 32; ++n) l[n] = sL[sb * SLS + n * 16 + sj];
        float m = l[0];
        #pragma unroll
        for (int n = 1; n < 32; ++n) m = fmaxf(m, l[n]);
        float Z = 0.f;
        #pragma unroll
        for (int n = 0; n < 32; ++n) { l[n] = __expf(l[n] - m); Z += l[n]; }
        const float inv = 1.0f / Z;
        #pragma unroll
        for (int n = 0; n < 32; ++n)
            sL[sb * SLS + n * 16 + sj] = fmaf(l[n], inv, sBias[n * 16 + sj]);
    }
    __syncthreads();

    // ---------------- pass 2: s[b,n,z] = sum_j c_j * u_j ----------------
    #pragma unroll 1
    for (int nq = 0; nq < 4; ++nq) {
        const int n = wv * 4 + nq;
        const uint4* pw = Wp + n * 256 + lane;
        wk[0] = pw[0]; wk[1] = pw[64]; wk[2] = pw[128]; wk[3] = pw[192];

        float s0 = 0.f, s1 = 0.f, s2 = 0.f, s3 = 0.f;
        #pragma unroll
        for (int jp = 0; jp < 8; ++jp) {
            float2 c2 = *reinterpret_cast<const float2*>(&sL[b16 * SLS + n * 16 + 2 * jp]);
            U4 a0 = maskA(wk[jp >> 1], (2 * jp) & 3);
            U4 a1 = maskA(wk[jp >> 1], (2 * jp + 1) & 3);
            U4 x0; x0.q = xq[jp >> 1];              // (2jp)>>2 == (2jp+1)>>2 == jp>>1
            f32x4 u0 = __builtin_amdgcn_mfma_f32_16x16x32_bf16(a0.v, x0.v, zero4, 0, 0, 0);
            f32x4 u1 = __builtin_amdgcn_mfma_f32_16x16x32_bf16(a1.v, x0.v, zero4, 0, 0, 0);
            s0 = fmaf(c2.x, u0[0], s0); s0 = fmaf(c2.y, u1[0], s0);
            s1 = fmaf(c2.x, u0[1], s1); s1 = fmaf(c2.y, u1[1], s1);
            s2 = fmaf(c2.x, u0[2], s2); s2 = fmaf(c2.y, u1[2], s2);
            s3 = fmaf(c2.x, u0[3], s3); s3 = fmaf(c2.y, u1[3], s3);
        }
        // lane (b16, q) -> Out[bb+b16][n][4q .. 4q+3]  (verified epilogue)
        float4* op = reinterpret_cast<float4*>(Out + (bb + b16) * 512 + n * 16 + q * 4);
        *op = make_float4(s0, s1, s2, s3);
    }
}

extern "C" void kernel_launch(void* const* d_in, const int* in_sizes, int n_in,
                              void* d_out, int out_size, void* d_ws, size_t ws_size,
                              hipStream_t stream) {
    const float* X  = (const float*)d_in[0];   // (16384, 16, 8) fp32
    const float* W  = (const float*)d_in[1];   // (32, 16, 8, 16) fp32
    const float* Bi = (const float*)d_in[2];   // (32, 16, 1) fp32
    float* Out = (float*)d_out;                // (16384, 32, 16) fp32

    uint4* Wp = (uint4*)d_ws;                  // 128 KiB packed Wk fragments
    prepack<<<32, 256, 0, stream>>>(W, Wp);
    caps<<<B_TOT / TBB, NTH, 0, stream>>>(X, Wp, Bi, Out);
}

// Round 8
// 106.687 us; speedup vs baseline: 1.0032x; 1.0032x over previous
//
#include <hip/hip_runtime.h>

// Problem constants (fixed by the reference)
#define B_TOT 16384
#define TBB   16        // batch rows per block
#define NTH   512       // 8 waves; wave wv handles n in [4wv, 4wv+4)
#define SLS   524       // f32 stride of sL row (verified R2/R4/R5/R6)

typedef short bf16x8 __attribute__((ext_vector_type(8)));
typedef float f32x4  __attribute__((ext_vector_type(4)));
union U4 { bf16x8 v; uint4 q; };

__device__ __forceinline__ unsigned f2bf(float f) {
    unsigned u = __float_as_uint(f);
    return (u + 0x7fffu + ((u >> 16) & 1u)) >> 16;   // RNE
}

__device__ __forceinline__ uint4 packrow(const float* src) {   // 8 W elems, i-stride 16
    uint4 o;
    o.x = f2bf(src[0])  | (f2bf(src[16])  << 16);
    o.y = f2bf(src[32]) | (f2bf(src[48])  << 16);
    o.z = f2bf(src[64]) | (f2bf(src[80])  << 16);
    o.w = f2bf(src[96]) | (f2bf(src[112]) << 16);
    return o;
}

// Wk[n][s][lane] (uint4): K=32 packed A-frag; lane (q=l>>4, z=l&15) holds
// W[n][4s+q][i=0..7][z]. Per-j fragments derived in registers by AND-masking
// the A side, lane-quarter q == (j&3) — the R4/R5/R6-VERIFIED path.
// NOTE (R7 lesson): masking the B (x) side instead FAILS on gfx950 despite
// the apparent A/B octet symmetry — do not swap operand sides here.
__global__ void prepack(const float* __restrict__ W, uint4* __restrict__ Wp)
{
    const int t = blockIdx.x * 256 + threadIdx.x;   // 8192 threads
    const int lane = t & 63, s = (t >> 6) & 3, n = t >> 8;
    const int q = lane >> 4, z = lane & 15;
    Wp[t] = packrow(W + (size_t)(n * 16 + 4 * s + q) * 128 + z);
}

// D-mapping (m89-verified, identical to PASSING R4/R5/R6): col = lane&15 = b, row = 4q+reg = z.
__global__ __launch_bounds__(NTH, 4)
void caps(const float* __restrict__ X, const uint4* __restrict__ Wp,
          const float* __restrict__ Bias, float* __restrict__ Out)
{
    __shared__ __align__(16) float sL[TBB * SLS];   // logits -> c+bias, f32 (33.5 KB)
    __shared__ float sBias[512];

    const int t    = threadIdx.x;
    const int lane = t & 63;
    const int wv   = t >> 6;          // 0..7
    const int b16  = lane & 15;       // D col = batch row
    const int q    = lane >> 4;       // lane quarter = K-octet = z-row group
    const long bb  = (long)blockIdx.x * TBB;

    sBias[t] = Bias[t];

    // per-octet lane masks: moct[c] = ~0 iff this lane's quarter q == c
    unsigned moct[4];
    #pragma unroll
    for (int c = 0; c < 4; ++c) moct[c] = (q == c) ? 0xffffffffu : 0u;

    // x B-frags, K=32 packed (4 j per frag): frag s, lane (q,b16) = x[b16][4s+q][0..7]
    uint4 xq[4];
    #pragma unroll
    for (int s = 0; s < 4; ++s) {
        const float* xs = X + (bb + b16) * 128 + (4 * s + q) * 8;
        float4 a = *reinterpret_cast<const float4*>(xs);
        float4 c = *reinterpret_cast<const float4*>(xs + 4);
        uint4 o;
        o.x = f2bf(a.x) | (f2bf(a.y) << 16);
        o.y = f2bf(a.z) | (f2bf(a.w) << 16);
        o.z = f2bf(c.x) | (f2bf(c.y) << 16);
        o.w = f2bf(c.z) | (f2bf(c.w) << 16);
        xq[s] = o;
    }

    const f32x4 zero4 = {0.f, 0.f, 0.f, 0.f};

    // masked per-j A-frag from the K=32 frag (4 v_and; bit-identical to R4 wj loads)
    auto maskA = [&](const uint4& wkf, int c) {
        U4 a;
        const unsigned m = moct[c];
        a.q.x = wkf.x & m; a.q.y = wkf.y & m;
        a.q.z = wkf.z & m; a.q.w = wkf.w & m;
        return a;
    };

    uint4 wk[4];

    // ---------------- pass 1: logits for this wave's 4 n ----------------
    #pragma unroll 1
    for (int nq = 0; nq < 4; ++nq) {
        const int n = wv * 4 + nq;
        const uint4* pw = Wp + n * 256 + lane;
        wk[0] = pw[0]; wk[1] = pw[64]; wk[2] = pw[128]; wk[3] = pw[192];

        f32x4 usum = zero4;                         // usum[b,z]: 4 chained MFMAs
        #pragma unroll
        for (int s = 0; s < 4; ++s) {
            U4 a;  a.q  = wk[s];
            U4 xb; xb.q = xq[s];
            usum = __builtin_amdgcn_mfma_f32_16x16x32_bf16(a.v, xb.v, usum, 0, 0, 0);
        }

        float lv[4];
        #pragma unroll
        for (int j = 0; j < 16; ++j) {              // 16 per-j MFMAs, zero loads
            U4 a  = maskA(wk[j >> 2], j & 3);
            U4 xb; xb.q = xq[j >> 2];
            f32x4 u = __builtin_amdgcn_mfma_f32_16x16x32_bf16(a.v, xb.v, zero4, 0, 0, 0);
            float p = u[0] * usum[0];
            p = fmaf(u[1], usum[1], p);
            p = fmaf(u[2], usum[2], p);
            p = fmaf(u[3], usum[3], p);
            p += __shfl_xor(p, 16);                 // sum the 4 z-quarters
            p += __shfl_xor(p, 32);
            lv[j & 3] = p * 0.25f;                  // /sqrt(D)
            if ((j & 3) == 3 && lane < 16)          // flush each 4-j chunk
                *reinterpret_cast<float4*>(&sL[b16 * SLS + n * 16 + (j - 3)]) =
                    make_float4(lv[0], lv[1], lv[2], lv[3]);
        }
    }
    __syncthreads();

    // ---------------- softmax over n (+ bias), one (b,j) per thread ----------------
    if (t < 256) {
        const int sb = t >> 4, sj = t & 15;
        float l[32];
        #pragma unroll
        for (int n = 0; n < 32; ++n) l[n] = sL[sb * SLS + n * 16 + sj];
        float m = l[0];
        #pragma unroll
        for (int n = 1; n < 32; ++n) m = fmaxf(m, l[n]);
        float Z = 0.f;
        #pragma unroll
        for (int n = 0; n < 32; ++n) { l[n] = __expf(l[n] - m); Z += l[n]; }
        const float inv = 1.0f / Z;
        #pragma unroll
        for (int n = 0; n < 32; ++n)
            sL[sb * SLS + n * 16 + sj] = fmaf(l[n], inv, sBias[n * 16 + sj]);
    }
    __syncthreads();

    // ---------------- pass 2: s[b,n,z] = sum_j c_j * u_j ----------------
    #pragma unroll 2
    for (int nq = 0; nq < 4; ++nq) {
        const int n = wv * 4 + nq;
        const uint4* pw = Wp + n * 256 + lane;
        uint4 wj0 = pw[0], wj1 = pw[64], wj2 = pw[128], wj3 = pw[192];

        float s0 = 0.f, s1 = 0.f, s2 = 0.f, s3 = 0.f;
        #pragma unroll
        for (int jp = 0; jp < 8; ++jp) {
            float2 c2 = *reinterpret_cast<const float2*>(&sL[b16 * SLS + n * 16 + 2 * jp]);
            const uint4& wks = (jp >> 1) == 0 ? wj0 : (jp >> 1) == 1 ? wj1
                             : (jp >> 1) == 2 ? wj2 : wj3;
            U4 a0 = maskA(wks, (2 * jp) & 3);
            U4 a1 = maskA(wks, (2 * jp + 1) & 3);
            U4 x0; x0.q = xq[jp >> 1];              // (2jp)>>2 == (2jp+1)>>2 == jp>>1
            f32x4 u0 = __builtin_amdgcn_mfma_f32_16x16x32_bf16(a0.v, x0.v, zero4, 0, 0, 0);
            f32x4 u1 = __builtin_amdgcn_mfma_f32_16x16x32_bf16(a1.v, x0.v, zero4, 0, 0, 0);
            s0 = fmaf(c2.x, u0[0], s0); s0 = fmaf(c2.y, u1[0], s0);
            s1 = fmaf(c2.x, u0[1], s1); s1 = fmaf(c2.y, u1[1], s1);
            s2 = fmaf(c2.x, u0[2], s2); s2 = fmaf(c2.y, u1[2], s2);
            s3 = fmaf(c2.x, u0[3], s3); s3 = fmaf(c2.y, u1[3], s3);
        }
        // lane (b16, q) -> Out[bb+b16][n][4q .. 4q+3]  (verified epilogue)
        float4* op = reinterpret_cast<float4*>(Out + (bb + b16) * 512 + n * 16 + q * 4);
        *op = make_float4(s0, s1, s2, s3);
    }
}

extern "C" void kernel_launch(void* const* d_in, const int* in_sizes, int n_in,
                              void* d_out, int out_size, void* d_ws, size_t ws_size,
                              hipStream_t stream) {
    const float* X  = (const float*)d_in[0];   // (16384, 16, 8) fp32
    const float* W  = (const float*)d_in[1];   // (32, 16, 8, 16) fp32
    const float* Bi = (const float*)d_in[2];   // (32, 16, 1) fp32
    float* Out = (float*)d_out;                // (16384, 32, 16) fp32

    uint4* Wp = (uint4*)d_ws;                  // 128 KiB packed Wk fragments
    prepack<<<32, 256, 0, stream>>>(W, Wp);
    caps<<<B_TOT / TBB, NTH, 0, stream>>>(X, Wp, Bi, Out);
}